// Round 4
// baseline (935.157 us; speedup 1.0000x reference)
//
#include <hip/hip_runtime.h>
#include <hip/hip_bf16.h>

// Problem constants (B, D, DOUT from reference)
#define BDIM 8192
#define DDIM 4096
#define DOUTD 4096

typedef __attribute__((ext_vector_type(8))) short short8;
typedef __attribute__((ext_vector_type(16))) float floatx16;

// round-to-nearest-even fp32 -> bf16 (bit pattern)
__device__ inline unsigned short f32_to_bf16_rne(float f) {
    unsigned int u = __float_as_uint(f);
    unsigned int lsb = (u >> 16) & 1u;
    u += 0x7fffu + lsb;
    return (unsigned short)(u >> 16);
}

// async global->LDS, 16B per lane; lds base must be wave-uniform
__device__ inline void gload_lds16(const void* g, void* lds) {
    __builtin_amdgcn_global_load_lds(
        (const __attribute__((address_space(1))) void*)g,
        (__attribute__((address_space(3))) void*)lds,
        16, 0, 0);
}

// Convert x (fp32 [B,D]) to bf16 natural (xb [B,D]) and transposed (xT [D,B]).
__global__ __launch_bounds__(256)
void convert_transpose_x(const float* __restrict__ x,
                         unsigned short* __restrict__ xb,
                         unsigned short* __restrict__ xT) {
    __shared__ __align__(16) unsigned short tile[64][72];  // [d][b], +8 pad
    const int t = threadIdx.x;
    const int tb = blockIdx.x * 64;   // b offset
    const int td = blockIdx.y * 64;   // d offset
#pragma unroll
    for (int p = 0; p < 4; ++p) {
        int c = t + p * 256;            // [0,1024)
        int row  = c >> 4;              // b-local
        int col4 = (c & 15) << 2;       // d-local
        float4 v = *(const float4*)&x[(size_t)(tb + row) * DDIM + td + col4];
        ushort4 o;
        o.x = f32_to_bf16_rne(v.x);
        o.y = f32_to_bf16_rne(v.y);
        o.z = f32_to_bf16_rne(v.z);
        o.w = f32_to_bf16_rne(v.w);
        *(ushort4*)&xb[(size_t)(tb + row) * DDIM + td + col4] = o;
        tile[col4 + 0][row] = o.x;
        tile[col4 + 1][row] = o.y;
        tile[col4 + 2][row] = o.z;
        tile[col4 + 3][row] = o.w;
    }
    __syncthreads();
#pragma unroll
    for (int p = 0; p < 4; ++p) {
        int c = t + p * 256;
        int drow = c >> 4;              // d-local
        int b4   = (c & 15) << 2;       // b-local
        ushort4 o = *(const ushort4*)&tile[drow][b4];
        *(ushort4*)&xT[(size_t)(td + drow) * BDIM + tb + b4] = o;
    }
}

// Elementwise fp32 -> bf16 for W
__global__ __launch_bounds__(256)
void convert_w_kernel(const float* __restrict__ W, unsigned short* __restrict__ Wb) {
    size_t i = ((size_t)blockIdx.x * 256 + threadIdx.x) * 4;
    float4 v = *(const float4*)&W[i];
    ushort4 o;
    o.x = f32_to_bf16_rne(v.x);
    o.y = f32_to_bf16_rne(v.y);
    o.z = f32_to_bf16_rne(v.z);
    o.w = f32_to_bf16_rne(v.w);
    *(ushort4*)&Wb[i] = o;
}

// compiler memory fence (zero instructions) + raw barrier
#define CFENCE() asm volatile("" ::: "memory")
#define BAR() do { CFENCE(); __builtin_amdgcn_s_barrier(); CFENCE(); } while (0)
#define MFMA_BF16 __builtin_amdgcn_mfma_f32_32x32x16_bf16

// ---------------------------------------------------------------------------
// C[m,n] = sum_k A[m,k]*B[n,k]  (+ bias[n]  or  + eps on diagonal)
// A: [M,K] bf16 row-major, B: [N,K] bf16 row-major, C: [M,N] fp32.
//
// 256x256 tile, BK=64, 512 threads = 8 waves (2M x 4N), wave tile 128x64.
// v4: K-SLICE phases (8 independent MFMAs each) with one-phase-ahead frag
// reads AND region-granular staging (the v3 WAR fix).
//
// LDS layout per operand per buffer (verified zero-conflict):
//   [region(2) x 16KB][row(256) x 64B][p(4) x 16B chunks],
//   stored chunk p = c2 ^ ((row>>2)&3), region r = k-half (k 32r..32r+31).
// Reads of K-slice s touch ONLY region s>>1 (rows of both halves).
// Stage unit (v4) = one operand x one REGION x all 256 rows (16KB):
//   wave w covers rows w*32..+32 (2 gload_lds16, dest linear); per-lane
//   global source carries inverse swizzle csrc = (l&3)^((l>>4)&3), so data
//   chunk csrc lands at stored pos l&3 = csrc ^ ((row>>2)&3). 
//
// Phase schedule (tile j, buf b=j&1; each phase: READS(next slice) + 1 stage,
// BAR, MFMA(current slice), [waits], BAR):
//   s0: MM slice0, read slice1,        stage A1(j+1)->buf b^1 reg1 ; vm8+lgkm0
//   s1: MM slice1, read slice2,        stage B0(j+2)->buf b  reg0
//   s2: MM slice2, read slice3,        stage A0(j+2)->buf b  reg0  ; vm8+lgkm0
//   s3: MM slice3, read slice0(j+1),   stage B1(j+2)->buf b  reg1
// WAR: reg0 of buf b last-read at s0 (lgkmcnt(0)+BAR before s1/s2 stages);
//      reg1 last-read at s2 (fence before s3/s0' stages). Reads and
//      same-phase stages always touch disjoint (buf,region).
// RAW ledger (2 loads/stage): outstanding 8->10->12->wait(8) repeating;
//   vmcnt(8) end-s0 drains exactly {B1,A1}(j+1) (needed s1),
//   vmcnt(8) end-s2 drains exactly {B0,A0}(j+1) (needed s3).
// Tail: stage tile index CLAMPED (never skipped) - ledger exact, clamped
// writes land only in dead (buf,region) areas.
// ---------------------------------------------------------------------------
template <bool HESS>
__global__ __launch_bounds__(512, 2)
void gemm256(const unsigned short* __restrict__ A,
             const unsigned short* __restrict__ B,
             const float* __restrict__ bias,
             float* __restrict__ C,
             int M, int N, int K) {
    __shared__ __align__(16) unsigned short As[32768];  // 2 buf x 2 region x 256 x 32
    __shared__ __align__(16) unsigned short Bs[32768];

    const int t    = threadIdx.x;
    const int lane = t & 63;
    const int w    = t >> 6;          // wave 0..7
    const int lm   = lane & 31;
    const int hi   = lane >> 5;       // k-half within MFMA operand
    const int key2 = (lm >> 2) & 3;   // read-side swizzle key (rows 32-aligned)
    const int wm   = w >> 2;          // 0..1  (M half of block tile)
    const int wn   = w & 3;           // 0..3  (N quarter)
    const size_t bm = (size_t)blockIdx.y * 256;
    const size_t bn = (size_t)blockIdx.x * 256;
    const int NT = K >> 6;            // K-tiles (>= 2 for our shapes)

    // ---- staging (per lane): wave w stages rows w*32..+32 of a region ----
    const int rsub = lane >> 2;                       // row within 16-row group
    const int csrc = (lane & 3) ^ ((lane >> 4) & 3);  // inverse-swizzled k-chunk
    const unsigned short* gA0 = A + (bm + w * 32 + rsub) * (size_t)K + csrc * 8;
    const unsigned short* gB0 = B + (bn + w * 32 + rsub) * (size_t)K + csrc * 8;
    char* ldsA = (char*)As + w * 2048;
    char* ldsB = (char*)Bs + w * 2048;
    const size_t rowK16 = (size_t)16 * K;   // 16 rows (shorts)

#define STAGE_A(tj, r, buf) do {                                   \
        const size_t _ko = (size_t)(tj) * 64 + (size_t)(r) * 32;   \
        char* _d = ldsA + (buf) * 32768 + (r) * 16384;             \
        gload_lds16(gA0 + _ko, _d);                                \
        gload_lds16(gA0 + _ko + rowK16, _d + 1024);                \
    } while (0)
#define STAGE_B(tj, r, buf) do {                                   \
        const size_t _ko = (size_t)(tj) * 64 + (size_t)(r) * 32;   \
        char* _d = ldsB + (buf) * 32768 + (r) * 16384;             \
        gload_lds16(gB0 + _ko, _d);                                \
        gload_lds16(gB0 + _ko + rowK16, _d + 1024);                \
    } while (0)

    // ---- read offsets (shorts) ----
    // slice s: addr = buf*16384 + (s>>1)*8192 + row*32 + (((s&1)*2+hi)^key2)*8
    const int arow0 = (wm * 128 +  0 + lm) * 32;
    const int arow1 = (wm * 128 + 32 + lm) * 32;
    const int arow2 = (wm * 128 + 64 + lm) * 32;
    const int arow3 = (wm * 128 + 96 + lm) * 32;
    const int brow0 = (  0 + wn * 32 + lm) * 32;
    const int brow1 = (128 + wn * 32 + lm) * 32;
    int pos[4];
#pragma unroll
    for (int s = 0; s < 4; ++s)
        pos[s] = (s >> 1) * 8192 + ((((s & 1) * 2 + hi) ^ key2) * 8);

    floatx16 acc[4][2];   // [m-tile][n-tile]
#pragma unroll
    for (int i = 0; i < 4; ++i)
#pragma unroll
        for (int j = 0; j < 2; ++j)
#pragma unroll
            for (int g = 0; g < 16; ++g)
                acc[i][j][g] = 0.f;

    short8 af[2][4], bf[2][2];   // [slice parity][tile]

#define READS(tt, bufofs, set) do {                                 \
        const int _o = (bufofs) + pos[tt];                          \
        af[set][0] = *(const short8*)&As[_o + arow0];               \
        af[set][1] = *(const short8*)&As[_o + arow1];               \
        af[set][2] = *(const short8*)&As[_o + arow2];               \
        af[set][3] = *(const short8*)&As[_o + arow3];               \
        bf[set][0] = *(const short8*)&Bs[_o + brow0];               \
        bf[set][1] = *(const short8*)&Bs[_o + brow1];               \
    } while (0)

#define MM(set) do {                                                        \
        acc[0][0] = MFMA_BF16(af[set][0], bf[set][0], acc[0][0], 0, 0, 0);  \
        acc[1][0] = MFMA_BF16(af[set][1], bf[set][0], acc[1][0], 0, 0, 0);  \
        acc[2][0] = MFMA_BF16(af[set][2], bf[set][0], acc[2][0], 0, 0, 0);  \
        acc[3][0] = MFMA_BF16(af[set][3], bf[set][0], acc[3][0], 0, 0, 0);  \
        acc[0][1] = MFMA_BF16(af[set][0], bf[set][1], acc[0][1], 0, 0, 0);  \
        acc[1][1] = MFMA_BF16(af[set][1], bf[set][1], acc[1][1], 0, 0, 0);  \
        acc[2][1] = MFMA_BF16(af[set][2], bf[set][1], acc[2][1], 0, 0, 0);  \
        acc[3][1] = MFMA_BF16(af[set][3], bf[set][1], acc[3][1], 0, 0, 0);  \
    } while (0)

    // ---- prologue: tile0 all 4 units + tile1 {B0,A0,B1}; drain tile0 ----
    STAGE_B(0, 0, 0); STAGE_A(0, 0, 0); STAGE_B(0, 1, 0); STAGE_A(0, 1, 0);
    STAGE_B(1, 0, 1); STAGE_A(1, 0, 1); STAGE_B(1, 1, 1);
    asm volatile("s_waitcnt vmcnt(6)" ::: "memory");
    BAR();
    READS(0, 0, 0);   // slice0 of tile0 -> set0

    for (int j = 0; j < NT; ++j) {
        const int b   = j & 1;
        const int ab  = b * 16384;          // shorts
        const int ab2 = (b ^ 1) * 16384;
        const int j1 = (j + 1 < NT) ? j + 1 : NT - 1;   // clamped (never skip)
        const int j2 = (j + 2 < NT) ? j + 2 : NT - 1;

        // ---- s0: MM slice0; read slice1->set1; stage A1(j+1)->buf^1 reg1 ----
        READS(1, ab, 1);
        STAGE_A(j1, 1, b ^ 1);
        BAR();
        __builtin_amdgcn_s_setprio(1);
        MM(0);
        __builtin_amdgcn_s_setprio(0);
        asm volatile("s_waitcnt vmcnt(8) lgkmcnt(0)" ::: "memory");
        __builtin_amdgcn_sched_barrier(0);
        BAR();

        // ---- s1: MM slice1; read slice2->set0; stage B0(j+2)->buf reg0 ----
        READS(2, ab, 0);
        STAGE_B(j2, 0, b);
        BAR();
        __builtin_amdgcn_s_setprio(1);
        MM(1);
        __builtin_amdgcn_s_setprio(0);
        BAR();

        // ---- s2: MM slice2; read slice3->set1; stage A0(j+2)->buf reg0 ----
        READS(3, ab, 1);
        STAGE_A(j2, 0, b);
        BAR();
        __builtin_amdgcn_s_setprio(1);
        MM(0);
        __builtin_amdgcn_s_setprio(0);
        asm volatile("s_waitcnt vmcnt(8) lgkmcnt(0)" ::: "memory");
        __builtin_amdgcn_sched_barrier(0);
        BAR();

        // ---- s3: MM slice3; read slice0(j+1)->set0; stage B1(j+2)->buf reg1
        READS(0, ab2, 0);
        STAGE_B(j2, 1, b);
        BAR();
        __builtin_amdgcn_s_setprio(1);
        MM(1);
        __builtin_amdgcn_s_setprio(0);
        BAR();
    }
    // don't leave DMA writes in flight past the loop
    asm volatile("s_waitcnt vmcnt(0)" ::: "memory");
#undef STAGE_A
#undef STAGE_B
#undef READS
#undef MM

    // ---- epilogue: D layout col = lane&31 (n), row = (reg&3)+8*(reg>>2)+4*hi
    float bv[2];
#pragma unroll
    for (int n2 = 0; n2 < 2; ++n2)
        bv[n2] = HESS ? 0.f : bias[bn + n2 * 128 + wn * 32 + lm];
#pragma unroll
    for (int m4 = 0; m4 < 4; ++m4) {
        const size_t mbase = bm + wm * 128 + m4 * 32 + 4 * hi;
#pragma unroll
        for (int n2 = 0; n2 < 2; ++n2) {
            const size_t n = bn + n2 * 128 + wn * 32 + lm;
#pragma unroll
            for (int reg = 0; reg < 16; ++reg) {
                const size_t m = mbase + (reg & 3) + 8 * (reg >> 2);
                float v = acc[m4][n2][reg] + bv[n2];
                if (HESS && m == n) v += 1e-4f;
                C[m * N + n] = v;
            }
        }
    }
}

extern "C" void kernel_launch(void* const* d_in, const int* in_sizes, int n_in,
                              void* d_out, int out_size, void* d_ws, size_t ws_size,
                              hipStream_t stream) {
    const float* x = (const float*)d_in[0];   // [8192, 4096]
    const float* W = (const float*)d_in[1];   // [4096, 4096]
    const float* b = (const float*)d_in[2];   // [4096]

    float* out  = (float*)d_out;                       // [8192, 4096]
    float* hess = out + (size_t)BDIM * DOUTD;          // [4096, 4096]

    // workspace layout (bf16): xb [B,D] | xT [D,B] | Wb [DOUT,D]  = 168 MB
    unsigned short* xb = (unsigned short*)d_ws;
    unsigned short* xT = xb + (size_t)BDIM * DDIM;
    unsigned short* Wb = xT + (size_t)BDIM * DDIM;

    convert_transpose_x<<<dim3(BDIM / 64, DDIM / 64), 256, 0, stream>>>(x, xb, xT);
    convert_w_kernel<<<((size_t)DOUTD * DDIM) / 1024, 256, 0, stream>>>(W, Wb);

    // out = x @ W.T + b : M=8192, N=4096, K=4096  (grid 16 x 32 = 512 blocks)
    gemm256<false><<<dim3(DOUTD / 256, BDIM / 256), 512, 0, stream>>>(
        xb, Wb, b, out, BDIM, DOUTD, DDIM);
    // hess = xT @ xT.T + eps*I : M=N=4096, K=8192  (grid 16 x 16 = 256 blocks)
    gemm256<true><<<dim3(DDIM / 256, DDIM / 256), 512, 0, stream>>>(
        xT, xT, nullptr, hess, DDIM, DDIM, BDIM);
}

// Round 7
// 863.090 us; speedup vs baseline: 1.0835x; 1.0835x over previous
//
#include <hip/hip_runtime.h>
#include <hip/hip_bf16.h>

// Problem constants (B, D, DOUT from reference)
#define BDIM 8192
#define DDIM 4096
#define DOUTD 4096

typedef __attribute__((ext_vector_type(8))) short short8;
typedef __attribute__((ext_vector_type(16))) float floatx16;

// round-to-nearest-even fp32 -> bf16 (bit pattern)
__device__ inline unsigned short f32_to_bf16_rne(float f) {
    unsigned int u = __float_as_uint(f);
    unsigned int lsb = (u >> 16) & 1u;
    u += 0x7fffu + lsb;
    return (unsigned short)(u >> 16);
}

// async global->LDS, 16B per lane; lds base must be wave-uniform
__device__ inline void gload_lds16(const void* g, void* lds) {
    __builtin_amdgcn_global_load_lds(
        (const __attribute__((address_space(1))) void*)g,
        (__attribute__((address_space(3))) void*)lds,
        16, 0, 0);
}

// Convert x (fp32 [B,D]) to bf16 natural (xb [B,D]) and transposed (xT [D,B]).
__global__ __launch_bounds__(256)
void convert_transpose_x(const float* __restrict__ x,
                         unsigned short* __restrict__ xb,
                         unsigned short* __restrict__ xT) {
    __shared__ __align__(16) unsigned short tile[64][72];  // [d][b], +8 pad
    const int t = threadIdx.x;
    const int tb = blockIdx.x * 64;   // b offset
    const int td = blockIdx.y * 64;   // d offset
#pragma unroll
    for (int p = 0; p < 4; ++p) {
        int c = t + p * 256;            // [0,1024)
        int row  = c >> 4;              // b-local
        int col4 = (c & 15) << 2;       // d-local
        float4 v = *(const float4*)&x[(size_t)(tb + row) * DDIM + td + col4];
        ushort4 o;
        o.x = f32_to_bf16_rne(v.x);
        o.y = f32_to_bf16_rne(v.y);
        o.z = f32_to_bf16_rne(v.z);
        o.w = f32_to_bf16_rne(v.w);
        *(ushort4*)&xb[(size_t)(tb + row) * DDIM + td + col4] = o;
        tile[col4 + 0][row] = o.x;
        tile[col4 + 1][row] = o.y;
        tile[col4 + 2][row] = o.z;
        tile[col4 + 3][row] = o.w;
    }
    __syncthreads();
#pragma unroll
    for (int p = 0; p < 4; ++p) {
        int c = t + p * 256;
        int drow = c >> 4;              // d-local
        int b4   = (c & 15) << 2;       // b-local
        ushort4 o = *(const ushort4*)&tile[drow][b4];
        *(ushort4*)&xT[(size_t)(td + drow) * BDIM + tb + b4] = o;
    }
}

// Elementwise fp32 -> bf16 for W
__global__ __launch_bounds__(256)
void convert_w_kernel(const float* __restrict__ W, unsigned short* __restrict__ Wb) {
    size_t i = ((size_t)blockIdx.x * 256 + threadIdx.x) * 4;
    float4 v = *(const float4*)&W[i];
    ushort4 o;
    o.x = f32_to_bf16_rne(v.x);
    o.y = f32_to_bf16_rne(v.y);
    o.z = f32_to_bf16_rne(v.z);
    o.w = f32_to_bf16_rne(v.w);
    *(ushort4*)&Wb[i] = o;
}

// compiler memory fence (zero instructions) + raw barrier
#define CFENCE() asm volatile("" ::: "memory")
#define BAR() do { CFENCE(); __builtin_amdgcn_s_barrier(); CFENCE(); } while (0)
#define MFMA_BF16 __builtin_amdgcn_mfma_f32_32x32x16_bf16

// ---------------------------------------------------------------------------
// C[m,n] = sum_k A[m,k]*B[n,k]  (+ bias[n]  or  + eps on diagonal)
// A: [M,K] bf16 row-major, B: [N,K] bf16 row-major, C: [M,N] fp32.
//
// v7 = verified v2 (858us, 0 bank conflicts) + K-loop unroll x2 (constexpr
// LDS buffer offsets -> all ds_read addresses reg+imm) + P1's 12-read burst
// split 6/6 (af0[0][*], bf[0..1] issue at END of previous P4).
//
// v6 bug fixes:
//  (a) early reads now issue AFTER P4's MFMA cluster (v6 clobbered
//      af0[0]/bf[0..1] before the MFMAs consuming them -> hess diag lost);
//  (b) prologue stages tile1 {Bh0, Ah0, Ah1} (v6 staged Bh1 twice and
//      never staged Ah1(1)).
//
// Safety argument (traced):
//  - Drain at P4 ENTRY: outstanding there = tile j+1's 8 loads + tile j+2's
//    6; vmcnt(6) retires exactly tile j+1 -> post-BAR, tile j+1 is resident
//    for ALL waves (vmcnt is per-wave; reads only after the barrier).
//  - Early reads (buf^1) vs outstanding DMAs after drain (all target buf b):
//    disjoint. Early-read areas are next overwritten at tile j+1's P2/P3/P4,
//    behind tile j+1's end-P1/P2/P3 lgkmcnt(0)+BAR fences which drain them.
//  - Register flow: af0[0]/bf[0..1] written by early reads, consumed by
//    tile j+1's P1 MFMAs; bf fully rewritten at P3 (after P2's consumers);
//    af0[0] rewritten only by the next early reads (after P4's consumers,
//    in program order).
//  - Ledger tail: j==NT-2 -> vmcnt(0); j==NT-1 -> no stages/early reads.
//
// LDS layout per operand per buffer: [region(2) x 16KB][row(256) x 64B]
//   [p(4) x 16B chunks], stored chunk p = c2 ^ ((row>>2)&3) (zero-conflict);
//   staging keeps global_load_lds dests linear, per-lane global source
//   carries the inverse swizzle.
// Stage units = half-tile (rows hx128, both regions); per K-tile:
//   P1: Bh1(j+1)->buf^1 | P2: Bh0(j+2)->buf | P3: Ah0(j+2)->buf
//   | P4-entry: Ah1(j+2)->buf, vmcnt(6|0), BAR.
// ---------------------------------------------------------------------------
template <bool HESS>
__global__ __launch_bounds__(512, 2)
void gemm256(const unsigned short* __restrict__ A,
             const unsigned short* __restrict__ B,
             const float* __restrict__ bias,
             float* __restrict__ C,
             int M, int N, int K) {
    __shared__ __align__(16) unsigned short As[32768];  // 2 buf x 2 region x 256 x 32
    __shared__ __align__(16) unsigned short Bs[32768];

    const int t    = threadIdx.x;
    const int lane = t & 63;
    const int w    = t >> 6;          // wave 0..7
    const int lm   = lane & 31;
    const int hi   = lane >> 5;       // k-half within MFMA operand
    const int key2 = (lm >> 2) & 3;   // read-side swizzle key (rows 32-aligned)
    const int wm   = w >> 2;          // 0..1  (M half of block tile)
    const int wn   = w & 3;           // 0..3  (N quarter)
    const size_t bm = (size_t)blockIdx.y * 256;
    const size_t bn = (size_t)blockIdx.x * 256;
    const int NT = K >> 6;            // K-tiles (even: 64 or 128 here)

    // ---- staging source pointers (per lane), inverse-swizzled k chunk ----
    const int kh_w = w >> 2;          // which 64B k-half this wave stages
    const int wq   = w & 3;           // 2KB stripe within (half-tile, region)
    const int rsub = lane >> 2;       // row within 16-row stripe
    const int csrc = (lane & 3) ^ ((lane >> 4) & 3);  // global k-chunk (of 4)
    const unsigned short* gA0 = A + (bm + wq * 32 + rsub) * (size_t)K + kh_w * 32 + csrc * 8;
    const unsigned short* gB0 = B + (bn + wq * 32 + rsub) * (size_t)K + kh_w * 32 + csrc * 8;
    char* ldsA = (char*)As + kh_w * 16384 + wq * 2048;  // + buf*32768 + h*8192
    char* ldsB = (char*)Bs + kh_w * 16384 + wq * 2048;
    const size_t rowK16 = (size_t)16 * K;   // 16 rows (shorts)
    const size_t halfK  = (size_t)128 * K;  // half-tile row jump (shorts)

#define STAGE_A(tj, h, buf) do {                                   \
        const size_t _ko = (size_t)(tj) * 64 + (size_t)(h) * halfK;\
        char* _d = ldsA + (buf) * 32768 + (h) * 8192;              \
        gload_lds16(gA0 + _ko, _d);                                \
        gload_lds16(gA0 + _ko + rowK16, _d + 1024);                \
    } while (0)
#define STAGE_B(tj, h, buf) do {                                   \
        const size_t _ko = (size_t)(tj) * 64 + (size_t)(h) * halfK;\
        char* _d = ldsB + (buf) * 32768 + (h) * 8192;              \
        gload_lds16(gB0 + _ko, _d);                                \
        gload_lds16(gB0 + _ko + rowK16, _d + 1024);                \
    } while (0)

    // ---- read offsets (shorts): addr = AB + ROWb + quad-offset + pos[s] ----
    const int AROWb = (wm * 128 + lm) * 32;  // + qm*2048 + mi*1024
    const int BROWb = (wn * 32 + lm) * 32;   // + qn*4096
    int pos[4];
#pragma unroll
    for (int s = 0; s < 4; ++s)
        pos[s] = (s >> 1) * 8192 + ((((s & 1) * 2 + hi) ^ key2) * 8);

    floatx16 acc[4][2];   // [qm*2+mi][qn]
#pragma unroll
    for (int i = 0; i < 4; ++i)
#pragma unroll
        for (int j = 0; j < 2; ++j)
#pragma unroll
            for (int g = 0; g < 16; ++g)
                acc[i][j][g] = 0.f;

    short8 af0[2][4], af1[2][4], bf[4];

    // early half of P1's reads (next tile, from AB2): af0[0][*] + bf[0..1]
#define READS_EARLY(AB2) do {                                              \
        _Pragma("unroll")                                                  \
        for (int s = 0; s < 4; ++s)                                        \
            af0[0][s] = *(const short8*)&As[(AB2) + AROWb + pos[s]];       \
        bf[0] = *(const short8*)&Bs[(AB2) + BROWb + pos[0]];               \
        bf[1] = *(const short8*)&Bs[(AB2) + BROWb + pos[1]];               \
    } while (0)

#define TILE_BODY(J, BUFC) do {                                            \
        constexpr int AB  = (BUFC) * 16384;                                \
        constexpr int AB2 = ((BUFC) ^ 1) * 16384;                          \
        /* -- P1: read af0[1], bf[2..3]; stage Bh1(J+1)->buf^1 -- */       \
        _Pragma("unroll")                                                  \
        for (int s = 0; s < 4; ++s)                                        \
            af0[1][s] = *(const short8*)&As[AB + AROWb + 1024 + pos[s]];   \
        bf[2] = *(const short8*)&Bs[AB + BROWb + pos[2]];                  \
        bf[3] = *(const short8*)&Bs[AB + BROWb + pos[3]];                  \
        if ((J) + 1 < NT) STAGE_B((J) + 1, 1, (BUFC) ^ 1);                 \
        BAR();                                                             \
        __builtin_amdgcn_s_setprio(1);                                     \
        _Pragma("unroll")                                                  \
        for (int s = 0; s < 4; ++s) {                                      \
            acc[0][0] = MFMA_BF16(af0[0][s], bf[s], acc[0][0], 0, 0, 0);   \
            acc[1][0] = MFMA_BF16(af0[1][s], bf[s], acc[1][0], 0, 0, 0);   \
        }                                                                  \
        __builtin_amdgcn_s_setprio(0);                                     \
        asm volatile("s_waitcnt lgkmcnt(0)" ::: "memory");                 \
        BAR();                                                             \
        /* -- P2: read af1; stage Bh0(J+2)->buf -- */                      \
        _Pragma("unroll")                                                  \
        for (int mi = 0; mi < 2; ++mi)                                     \
            _Pragma("unroll")                                              \
            for (int s = 0; s < 4; ++s)                                    \
                af1[mi][s] = *(const short8*)&As[AB + AROWb + 2048 + mi * 1024 + pos[s]]; \
        if ((J) + 2 < NT) STAGE_B((J) + 2, 0, (BUFC));                     \
        BAR();                                                             \
        __builtin_amdgcn_s_setprio(1);                                     \
        _Pragma("unroll")                                                  \
        for (int s = 0; s < 4; ++s) {                                      \
            acc[2][0] = MFMA_BF16(af1[0][s], bf[s], acc[2][0], 0, 0, 0);   \
            acc[3][0] = MFMA_BF16(af1[1][s], bf[s], acc[3][0], 0, 0, 0);   \
        }                                                                  \
        __builtin_amdgcn_s_setprio(0);                                     \
        asm volatile("s_waitcnt lgkmcnt(0)" ::: "memory");                 \
        BAR();                                                             \
        /* -- P3: read bf qn1; stage Ah0(J+2)->buf -- */                   \
        _Pragma("unroll")                                                  \
        for (int s = 0; s < 4; ++s)                                        \
            bf[s] = *(const short8*)&Bs[AB + BROWb + 4096 + pos[s]];       \
        if ((J) + 2 < NT) STAGE_A((J) + 2, 0, (BUFC));                     \
        BAR();                                                             \
        __builtin_amdgcn_s_setprio(1);                                     \
        _Pragma("unroll")                                                  \
        for (int s = 0; s < 4; ++s) {                                      \
            acc[2][1] = MFMA_BF16(af1[0][s], bf[s], acc[2][1], 0, 0, 0);   \
            acc[3][1] = MFMA_BF16(af1[1][s], bf[s], acc[3][1], 0, 0, 0);   \
        }                                                                  \
        __builtin_amdgcn_s_setprio(0);                                     \
        asm volatile("s_waitcnt lgkmcnt(0)" ::: "memory");                 \
        BAR();                                                             \
        /* -- P4: stage Ah1(J+2)->buf; vmcnt drain; BAR; MFMA; THEN early reads -- */\
        if ((J) + 2 < NT) STAGE_A((J) + 2, 1, (BUFC));                     \
        if ((J) < NT - 2)       asm volatile("s_waitcnt vmcnt(6)" ::: "memory"); \
        else if ((J) == NT - 2) asm volatile("s_waitcnt vmcnt(0)" ::: "memory"); \
        BAR();                                                             \
        __builtin_amdgcn_s_setprio(1);                                     \
        _Pragma("unroll")                                                  \
        for (int s = 0; s < 4; ++s) {                                      \
            acc[0][1] = MFMA_BF16(af0[0][s], bf[s], acc[0][1], 0, 0, 0);   \
            acc[1][1] = MFMA_BF16(af0[1][s], bf[s], acc[1][1], 0, 0, 0);   \
        }                                                                  \
        __builtin_amdgcn_s_setprio(0);                                     \
        if ((J) + 1 < NT) READS_EARLY(AB2);                                \
        BAR();                                                             \
    } while (0)

    // ---- prologue: tile0 full + tile1 {Bh0,Ah0,Ah1}; drain tile0 ----
    STAGE_B(0, 0, 0); STAGE_A(0, 0, 0); STAGE_B(0, 1, 0); STAGE_A(0, 1, 0);
    STAGE_B(1, 0, 1); STAGE_A(1, 0, 1); STAGE_A(1, 1, 1);
    asm volatile("s_waitcnt vmcnt(6)" ::: "memory");
    BAR();
    READS_EARLY(0);   // tile0: af0[0][*] + bf[0..1] from buf0 (post-BAR: safe)

    for (int jj = 0; jj < NT; jj += 2) {
        TILE_BODY(jj, 0);
        TILE_BODY(jj + 1, 1);
    }
#undef STAGE_A
#undef STAGE_B
#undef READS_EARLY
#undef TILE_BODY

    // ---- epilogue: D layout col = lane&31 (n), row = (reg&3)+8*(reg>>2)+4*hi
    float bv[2];
#pragma unroll
    for (int n2 = 0; n2 < 2; ++n2)
        bv[n2] = HESS ? 0.f : bias[bn + n2 * 128 + wn * 32 + lm];
#pragma unroll
    for (int m4 = 0; m4 < 4; ++m4) {
        const size_t mbase = bm + wm * 128 + m4 * 32 + 4 * hi;
#pragma unroll
        for (int n2 = 0; n2 < 2; ++n2) {
            const size_t n = bn + n2 * 128 + wn * 32 + lm;
#pragma unroll
            for (int reg = 0; reg < 16; ++reg) {
                const size_t m = mbase + (reg & 3) + 8 * (reg >> 2);
                float v = acc[m4][n2][reg] + bv[n2];
                if (HESS && m == n) v += 1e-4f;
                C[m * N + n] = v;
            }
        }
    }
}

extern "C" void kernel_launch(void* const* d_in, const int* in_sizes, int n_in,
                              void* d_out, int out_size, void* d_ws, size_t ws_size,
                              hipStream_t stream) {
    const float* x = (const float*)d_in[0];   // [8192, 4096]
    const float* W = (const float*)d_in[1];   // [4096, 4096]
    const float* b = (const float*)d_in[2];   // [4096]

    float* out  = (float*)d_out;                       // [8192, 4096]
    float* hess = out + (size_t)BDIM * DOUTD;          // [4096, 4096]

    // workspace layout (bf16): xb [B,D] | xT [D,B] | Wb [DOUT,D]  = 168 MB
    unsigned short* xb = (unsigned short*)d_ws;
    unsigned short* xT = xb + (size_t)BDIM * DDIM;
    unsigned short* Wb = xT + (size_t)BDIM * DDIM;

    convert_transpose_x<<<dim3(BDIM / 64, DDIM / 64), 256, 0, stream>>>(x, xb, xT);
    convert_w_kernel<<<((size_t)DOUTD * DDIM) / 1024, 256, 0, stream>>>(W, Wb);

    // out = x @ W.T + b : M=8192, N=4096, K=4096  (grid 16 x 32 = 512 blocks)
    gemm256<false><<<dim3(DOUTD / 256, BDIM / 256), 512, 0, stream>>>(
        xb, Wb, b, out, BDIM, DOUTD, DDIM);
    // hess = xT @ xT.T + eps*I : M=N=4096, K=8192  (grid 16 x 16 = 256 blocks)
    gemm256<true><<<dim3(DDIM / 256, DDIM / 256), 512, 0, stream>>>(
        xT, xT, nullptr, hess, DDIM, DDIM, BDIM);
}

// Round 8
// 856.826 us; speedup vs baseline: 1.0914x; 1.0073x over previous
//
#include <hip/hip_runtime.h>
#include <hip/hip_bf16.h>

// Problem constants (B, D, DOUT from reference)
#define BDIM 8192
#define DDIM 4096
#define DOUTD 4096

typedef __attribute__((ext_vector_type(8))) short short8;
typedef __attribute__((ext_vector_type(16))) float floatx16;

// round-to-nearest-even fp32 -> bf16 (bit pattern)
__device__ inline unsigned short f32_to_bf16_rne(float f) {
    unsigned int u = __float_as_uint(f);
    unsigned int lsb = (u >> 16) & 1u;
    u += 0x7fffu + lsb;
    return (unsigned short)(u >> 16);
}

// async global->LDS, 16B per lane; lds base must be wave-uniform
__device__ inline void gload_lds16(const void* g, void* lds) {
    __builtin_amdgcn_global_load_lds(
        (const __attribute__((address_space(1))) void*)g,
        (__attribute__((address_space(3))) void*)lds,
        16, 0, 0);
}

// Convert x (fp32 [B,D]) to bf16 natural (xb [B,D]) and transposed (xT [D,B]).
__global__ __launch_bounds__(256)
void convert_transpose_x(const float* __restrict__ x,
                         unsigned short* __restrict__ xb,
                         unsigned short* __restrict__ xT) {
    __shared__ __align__(16) unsigned short tile[64][72];  // [d][b], +8 pad
    const int t = threadIdx.x;
    const int tb = blockIdx.x * 64;   // b offset
    const int td = blockIdx.y * 64;   // d offset
#pragma unroll
    for (int p = 0; p < 4; ++p) {
        int c = t + p * 256;            // [0,1024)
        int row  = c >> 4;              // b-local
        int col4 = (c & 15) << 2;       // d-local
        float4 v = *(const float4*)&x[(size_t)(tb + row) * DDIM + td + col4];
        ushort4 o;
        o.x = f32_to_bf16_rne(v.x);
        o.y = f32_to_bf16_rne(v.y);
        o.z = f32_to_bf16_rne(v.z);
        o.w = f32_to_bf16_rne(v.w);
        *(ushort4*)&xb[(size_t)(tb + row) * DDIM + td + col4] = o;
        tile[col4 + 0][row] = o.x;
        tile[col4 + 1][row] = o.y;
        tile[col4 + 2][row] = o.z;
        tile[col4 + 3][row] = o.w;
    }
    __syncthreads();
#pragma unroll
    for (int p = 0; p < 4; ++p) {
        int c = t + p * 256;
        int drow = c >> 4;              // d-local
        int b4   = (c & 15) << 2;       // b-local
        ushort4 o = *(const ushort4*)&tile[drow][b4];
        *(ushort4*)&xT[(size_t)(td + drow) * BDIM + tb + b4] = o;
    }
}

// Elementwise fp32 -> bf16 for W
__global__ __launch_bounds__(256)
void convert_w_kernel(const float* __restrict__ W, unsigned short* __restrict__ Wb) {
    size_t i = ((size_t)blockIdx.x * 256 + threadIdx.x) * 4;
    float4 v = *(const float4*)&W[i];
    ushort4 o;
    o.x = f32_to_bf16_rne(v.x);
    o.y = f32_to_bf16_rne(v.y);
    o.z = f32_to_bf16_rne(v.z);
    o.w = f32_to_bf16_rne(v.w);
    *(ushort4*)&Wb[i] = o;
}

// compiler memory fence (zero instructions) + raw barrier
#define CFENCE() asm volatile("" ::: "memory")
#define BAR() do { CFENCE(); __builtin_amdgcn_s_barrier(); CFENCE(); } while (0)
#define MFMA_BF16 __builtin_amdgcn_mfma_f32_32x32x16_bf16

// ---------------------------------------------------------------------------
// C[m,n] = sum_k A[m,k]*B[n,k]  (+ bias[n]  or  + eps on diagonal)
// A: [M,K] bf16 row-major, B: [N,K] bf16 row-major, C: [M,N] fp32.
//
// v8 = v7 (verified, 277us/gemm) with the per-tile MFMA work RE-PARTITIONED
// into phases of 4 independent chains of length 2 (was 2 chains of 4):
//   P1: accs {0,1}x{0,1} over k-slices s=0,1   (af0 s01, bf[*][s01])
//   P2: accs {0,1}x{0,1} over s=2,3            (af0 s23, bf[*][s23])
//   P3: accs {2,3}x{0,1} over s=0,1            (af1 s01, bf held)
//   P4: accs {2,3}x{0,1} over s=2,3            (af1 s23, bf held)
// Rationale: s_barrier does not wait on MFMA completion; a wave exits the
// MFMA region as soon as issue completes. Chains of 4 scoreboard-stall the
// wave ~160cyc per region (serializing LDS-drain vs MFMA across the CU);
// chains of 2 with 4-way ILP exit in ~80cyc, letting next-phase ds_reads
// drain while the MFMA pipe grinds (m201's overlap mechanism).
//
// Reads per phase (6/8/4/6, identical totals to v7):
//   P4-post-MFMA (early, next tile buf^1): af0[mi][s01] (4) + bf[0][s01] (2)
//   P1 own: af0[mi][s23] (4) + bf[1][s01] (2)
//   P2 own: bf[0][s23] (2) + bf[1][s23] (2) + af1[mi][s01] (4)
//   P3 own: af1[mi][s23] (4)
// Early-read WAR: af0 s01 / bf[0] s01 are dead after P1/P3 consumers and
// rewritten after P4's MFMAs issue (in-order). Early reads happen only
// after the P4-entry vmcnt(6)+BAR (tile j+1 resident for ALL waves).
//
// Staging, ledger, fences: byte-identical to v7:
//   P1: Bh1(j+1)->buf^1 | P2: Bh0(j+2)->buf | P3: Ah0(j+2)->buf
//   | P4-entry: Ah1(j+2)->buf, vmcnt(6) (==vmcnt(0) at j==NT-2), BAR.
//   lgkmcnt(0) at end of P1/P2/P3 (post-MFMA, ~free) preserves the WAR
//   discipline for stage overwrites.
// LDS layout per operand per buffer: [region(2) x 16KB][row(256) x 64B]
//   [p(4) x 16B chunks], chunk p = c2 ^ ((row>>2)&3) (zero-conflict);
//   global_load_lds dests linear; per-lane global source inverse-swizzled.
// ---------------------------------------------------------------------------
template <bool HESS>
__global__ __launch_bounds__(512, 2)
void gemm256(const unsigned short* __restrict__ A,
             const unsigned short* __restrict__ B,
             const float* __restrict__ bias,
             float* __restrict__ C,
             int M, int N, int K) {
    __shared__ __align__(16) unsigned short As[32768];  // 2 buf x 2 region x 256 x 32
    __shared__ __align__(16) unsigned short Bs[32768];

    const int t    = threadIdx.x;
    const int lane = t & 63;
    const int w    = t >> 6;          // wave 0..7
    const int lm   = lane & 31;
    const int hi   = lane >> 5;       // k-half within MFMA operand
    const int key2 = (lm >> 2) & 3;   // read-side swizzle key (rows 32-aligned)
    const int wm   = w >> 2;          // 0..1  (M half of block tile)
    const int wn   = w & 3;           // 0..3  (N quarter)
    const size_t bm = (size_t)blockIdx.y * 256;
    const size_t bn = (size_t)blockIdx.x * 256;
    const int NT = K >> 6;            // K-tiles (even: 64 or 128 here)

    // ---- staging source pointers (per lane), inverse-swizzled k chunk ----
    const int kh_w = w >> 2;          // which 64B k-half this wave stages
    const int wq   = w & 3;           // 2KB stripe within (half-tile, region)
    const int rsub = lane >> 2;       // row within 16-row stripe
    const int csrc = (lane & 3) ^ ((lane >> 4) & 3);  // global k-chunk (of 4)
    const unsigned short* gA0 = A + (bm + wq * 32 + rsub) * (size_t)K + kh_w * 32 + csrc * 8;
    const unsigned short* gB0 = B + (bn + wq * 32 + rsub) * (size_t)K + kh_w * 32 + csrc * 8;
    char* ldsA = (char*)As + kh_w * 16384 + wq * 2048;  // + buf*32768 + h*8192
    char* ldsB = (char*)Bs + kh_w * 16384 + wq * 2048;
    const size_t rowK16 = (size_t)16 * K;   // 16 rows (shorts)
    const size_t halfK  = (size_t)128 * K;  // half-tile row jump (shorts)

#define STAGE_A(tj, h, buf) do {                                   \
        const size_t _ko = (size_t)(tj) * 64 + (size_t)(h) * halfK;\
        char* _d = ldsA + (buf) * 32768 + (h) * 8192;              \
        gload_lds16(gA0 + _ko, _d);                                \
        gload_lds16(gA0 + _ko + rowK16, _d + 1024);                \
    } while (0)
#define STAGE_B(tj, h, buf) do {                                   \
        const size_t _ko = (size_t)(tj) * 64 + (size_t)(h) * halfK;\
        char* _d = ldsB + (buf) * 32768 + (h) * 8192;              \
        gload_lds16(gB0 + _ko, _d);                                \
        gload_lds16(gB0 + _ko + rowK16, _d + 1024);                \
    } while (0)

    // ---- read offsets (shorts): addr = AB + ROWb + quad-offset + pos[s] ----
    const int AROWb = (wm * 128 + lm) * 32;  // + mi*1024 (af0) / +2048+mi*1024 (af1)
    const int BROWb = (wn * 32 + lm) * 32;   // + qn*4096
    int pos[4];
#pragma unroll
    for (int s = 0; s < 4; ++s)
        pos[s] = (s >> 1) * 8192 + ((((s & 1) * 2 + hi) ^ key2) * 8);

    floatx16 acc[4][2];   // [m-tile][qn]
#pragma unroll
    for (int i = 0; i < 4; ++i)
#pragma unroll
        for (int j = 0; j < 2; ++j)
#pragma unroll
            for (int g = 0; g < 16; ++g)
                acc[i][j][g] = 0.f;

    short8 af0[2][4], af1[2][4], bf[2][4];   // [mi][s] / [qn][s]

    // early reads (next tile, from AB2): af0[mi][s01] + bf[0][s01]
#define READS_EARLY(AB2) do {                                              \
        _Pragma("unroll")                                                  \
        for (int mi = 0; mi < 2; ++mi) {                                   \
            af0[mi][0] = *(const short8*)&As[(AB2) + AROWb + mi * 1024 + pos[0]]; \
            af0[mi][1] = *(const short8*)&As[(AB2) + AROWb + mi * 1024 + pos[1]]; \
        }                                                                  \
        bf[0][0] = *(const short8*)&Bs[(AB2) + BROWb + pos[0]];            \
        bf[0][1] = *(const short8*)&Bs[(AB2) + BROWb + pos[1]];            \
    } while (0)

#define TILE_BODY(J, BUFC) do {                                            \
        constexpr int AB  = (BUFC) * 16384;                                \
        constexpr int AB2 = ((BUFC) ^ 1) * 16384;                          \
        /* -- P1: read af0 s23 + bf[1] s01; stage Bh1(J+1)->buf^1;      */ \
        /*    MFMA accs{0,1}x{0,1} s=0,1                                */ \
        _Pragma("unroll")                                                  \
        for (int mi = 0; mi < 2; ++mi) {                                   \
            af0[mi][2] = *(const short8*)&As[AB + AROWb + mi * 1024 + pos[2]]; \
            af0[mi][3] = *(const short8*)&As[AB + AROWb + mi * 1024 + pos[3]]; \
        }                                                                  \
        bf[1][0] = *(const short8*)&Bs[AB + BROWb + 4096 + pos[0]];        \
        bf[1][1] = *(const short8*)&Bs[AB + BROWb + 4096 + pos[1]];        \
        if ((J) + 1 < NT) STAGE_B((J) + 1, 1, (BUFC) ^ 1);                 \
        BAR();                                                             \
        __builtin_amdgcn_s_setprio(1);                                     \
        _Pragma("unroll")                                                  \
        for (int s = 0; s < 2; ++s) {                                      \
            acc[0][0] = MFMA_BF16(af0[0][s], bf[0][s], acc[0][0], 0, 0, 0);\
            acc[1][0] = MFMA_BF16(af0[1][s], bf[0][s], acc[1][0], 0, 0, 0);\
            acc[0][1] = MFMA_BF16(af0[0][s], bf[1][s], acc[0][1], 0, 0, 0);\
            acc[1][1] = MFMA_BF16(af0[1][s], bf[1][s], acc[1][1], 0, 0, 0);\
        }                                                                  \
        __builtin_amdgcn_s_setprio(0);                                     \
        asm volatile("s_waitcnt lgkmcnt(0)" ::: "memory");                 \
        BAR();                                                             \
        /* -- P2: read bf s23 (both qn) + af1 s01; stage Bh0(J+2)->buf; */ \
        /*    MFMA accs{0,1}x{0,1} s=2,3                                */ \
        bf[0][2] = *(const short8*)&Bs[AB + BROWb + pos[2]];               \
        bf[0][3] = *(const short8*)&Bs[AB + BROWb + pos[3]];               \
        bf[1][2] = *(const short8*)&Bs[AB + BROWb + 4096 + pos[2]];        \
        bf[1][3] = *(const short8*)&Bs[AB + BROWb + 4096 + pos[3]];        \
        _Pragma("unroll")                                                  \
        for (int mi = 0; mi < 2; ++mi) {                                   \
            af1[mi][0] = *(const short8*)&As[AB + AROWb + 2048 + mi * 1024 + pos[0]]; \
            af1[mi][1] = *(const short8*)&As[AB + AROWb + 2048 + mi * 1024 + pos[1]]; \
        }                                                                  \
        if ((J) + 2 < NT) STAGE_B((J) + 2, 0, (BUFC));                     \
        BAR();                                                             \
        __builtin_amdgcn_s_setprio(1);                                     \
        _Pragma("unroll")                                                  \
        for (int s = 2; s < 4; ++s) {                                      \
            acc[0][0] = MFMA_BF16(af0[0][s], bf[0][s], acc[0][0], 0, 0, 0);\
            acc[1][0] = MFMA_BF16(af0[1][s], bf[0][s], acc[1][0], 0, 0, 0);\
            acc[0][1] = MFMA_BF16(af0[0][s], bf[1][s], acc[0][1], 0, 0, 0);\
            acc[1][1] = MFMA_BF16(af0[1][s], bf[1][s], acc[1][1], 0, 0, 0);\
        }                                                                  \
        __builtin_amdgcn_s_setprio(0);                                     \
        asm volatile("s_waitcnt lgkmcnt(0)" ::: "memory");                 \
        BAR();                                                             \
        /* -- P3: read af1 s23; stage Ah0(J+2)->buf;                    */ \
        /*    MFMA accs{2,3}x{0,1} s=0,1                                */ \
        _Pragma("unroll")                                                  \
        for (int mi = 0; mi < 2; ++mi) {                                   \
            af1[mi][2] = *(const short8*)&As[AB + AROWb + 2048 + mi * 1024 + pos[2]]; \
            af1[mi][3] = *(const short8*)&As[AB + AROWb + 2048 + mi * 1024 + pos[3]]; \
        }                                                                  \
        if ((J) + 2 < NT) STAGE_A((J) + 2, 0, (BUFC));                     \
        BAR();                                                             \
        __builtin_amdgcn_s_setprio(1);                                     \
        _Pragma("unroll")                                                  \
        for (int s = 0; s < 2; ++s) {                                      \
            acc[2][0] = MFMA_BF16(af1[0][s], bf[0][s], acc[2][0], 0, 0, 0);\
            acc[3][0] = MFMA_BF16(af1[1][s], bf[0][s], acc[3][0], 0, 0, 0);\
            acc[2][1] = MFMA_BF16(af1[0][s], bf[1][s], acc[2][1], 0, 0, 0);\
            acc[3][1] = MFMA_BF16(af1[1][s], bf[1][s], acc[3][1], 0, 0, 0);\
        }                                                                  \
        __builtin_amdgcn_s_setprio(0);                                     \
        asm volatile("s_waitcnt lgkmcnt(0)" ::: "memory");                 \
        BAR();                                                             \
        /* -- P4: stage Ah1(J+2)->buf; vmcnt drain; BAR;                */ \
        /*    MFMA accs{2,3}x{0,1} s=2,3; THEN early reads (buf^1)      */ \
        if ((J) + 2 < NT) STAGE_A((J) + 2, 1, (BUFC));                     \
        if ((J) < NT - 2)       asm volatile("s_waitcnt vmcnt(6)" ::: "memory"); \
        else if ((J) == NT - 2) asm volatile("s_waitcnt vmcnt(0)" ::: "memory"); \
        BAR();                                                             \
        __builtin_amdgcn_s_setprio(1);                                     \
        _Pragma("unroll")                                                  \
        for (int s = 2; s < 4; ++s) {                                      \
            acc[2][0] = MFMA_BF16(af1[0][s], bf[0][s], acc[2][0], 0, 0, 0);\
            acc[3][0] = MFMA_BF16(af1[1][s], bf[0][s], acc[3][0], 0, 0, 0);\
            acc[2][1] = MFMA_BF16(af1[0][s], bf[1][s], acc[2][1], 0, 0, 0);\
            acc[3][1] = MFMA_BF16(af1[1][s], bf[1][s], acc[3][1], 0, 0, 0);\
        }                                                                  \
        __builtin_amdgcn_s_setprio(0);                                     \
        if ((J) + 1 < NT) READS_EARLY(AB2);                                \
        BAR();                                                             \
    } while (0)

    // ---- prologue: tile0 full + tile1 {Bh0,Ah0,Ah1}; drain tile0 ----
    STAGE_B(0, 0, 0); STAGE_A(0, 0, 0); STAGE_B(0, 1, 0); STAGE_A(0, 1, 0);
    STAGE_B(1, 0, 1); STAGE_A(1, 0, 1); STAGE_A(1, 1, 1);
    asm volatile("s_waitcnt vmcnt(6)" ::: "memory");
    BAR();
    READS_EARLY(0);   // tile0: af0 s01 + bf[0] s01 from buf0 (post-BAR: safe)

    for (int jj = 0; jj < NT; jj += 2) {
        TILE_BODY(jj, 0);
        TILE_BODY(jj + 1, 1);
    }
#undef STAGE_A
#undef STAGE_B
#undef READS_EARLY
#undef TILE_BODY

    // ---- epilogue: D layout col = lane&31 (n), row = (reg&3)+8*(reg>>2)+4*hi
    float bv[2];
#pragma unroll
    for (int n2 = 0; n2 < 2; ++n2)
        bv[n2] = HESS ? 0.f : bias[bn + n2 * 128 + wn * 32 + lm];
#pragma unroll
    for (int m4 = 0; m4 < 4; ++m4) {
        const size_t mbase = bm + wm * 128 + m4 * 32 + 4 * hi;
#pragma unroll
        for (int n2 = 0; n2 < 2; ++n2) {
            const size_t n = bn + n2 * 128 + wn * 32 + lm;
#pragma unroll
            for (int reg = 0; reg < 16; ++reg) {
                const size_t m = mbase + (reg & 3) + 8 * (reg >> 2);
                float v = acc[m4][n2][reg] + bv[n2];
                if (HESS && m == n) v += 1e-4f;
                C[m * N + n] = v;
            }
        }
    }
}

extern "C" void kernel_launch(void* const* d_in, const int* in_sizes, int n_in,
                              void* d_out, int out_size, void* d_ws, size_t ws_size,
                              hipStream_t stream) {
    const float* x = (const float*)d_in[0];   // [8192, 4096]
    const float* W = (const float*)d_in[1];   // [4096, 4096]
    const float* b = (const float*)d_in[2];   // [4096]

    float* out  = (float*)d_out;                       // [8192, 4096]
    float* hess = out + (size_t)BDIM * DOUTD;          // [4096, 4096]

    // workspace layout (bf16): xb [B,D] | xT [D,B] | Wb [DOUT,D]  = 168 MB
    unsigned short* xb = (unsigned short*)d_ws;
    unsigned short* xT = xb + (size_t)BDIM * DDIM;
    unsigned short* Wb = xT + (size_t)BDIM * DDIM;

    convert_transpose_x<<<dim3(BDIM / 64, DDIM / 64), 256, 0, stream>>>(x, xb, xT);
    convert_w_kernel<<<((size_t)DOUTD * DDIM) / 1024, 256, 0, stream>>>(W, Wb);

    // out = x @ W.T + b : M=8192, N=4096, K=4096  (grid 16 x 32 = 512 blocks)
    gemm256<false><<<dim3(DOUTD / 256, BDIM / 256), 512, 0, stream>>>(
        xb, Wb, b, out, BDIM, DOUTD, DDIM);
    // hess = xT @ xT.T + eps*I : M=N=4096, K=8192  (grid 16 x 16 = 256 blocks)
    gemm256<true><<<dim3(DDIM / 256, DDIM / 256), 512, 0, stream>>>(
        xT, xT, nullptr, hess, DDIM, DDIM, BDIM);
}